// Round 7
// baseline (133.754 us; speedup 1.0000x reference)
//
#include <hip/hip_runtime.h>
#include <cstddef>

#define HH 512
#define WW 512
#define BB 8
#define TX 64
#define TY 32

// ws layout (floats):
//   [0..72)      keff_edge  (3*3)*8ch
//   [72..193)    Keff11     11*11
//   [256..1280)  F32-bank (grad filters, 32x32x16 A-frags): 2 tiles x 64 ln x 8 bf16
//                A_t[ch=ln&31][k=(ln>>5)*8+j] = (k<9) ? K_t[k*32+ch] : 0
//   [1280..4096) KT2-bank (kappa x-Toeplitz B-frags): 11 a x 64 lanes x 8 bf16
//                B_a[k=(ln>>4)*8+j][n=ln&15] = kef[a][k-n] if 0<=k-n<=10 else 0
//   [4096..5376) SMB-bank (smoother x-Toeplitz B-frags): 5 a x 64 lanes x 8 bf16
//                B_a[k][n] = sm[a*5+(k-n)] if 0<=k-n<=4 else 0
#define F0    256
#define KT0   1280
#define SM0   4096
#define WS_NEEDED_BYTES ((size_t)5376 * 4)

typedef __attribute__((ext_vector_type(8))) short short8;
typedef __attribute__((ext_vector_type(4))) float float4v;
typedef __attribute__((ext_vector_type(2))) float float2v;
typedef __attribute__((ext_vector_type(16))) float float16v;

__device__ inline unsigned short f2bf(float f) {   // fp32 -> bf16 RNE
  unsigned u = __builtin_bit_cast(unsigned, f);
  unsigned r = (u + 0x7FFFu + ((u >> 16) & 1u)) >> 16;
  return (unsigned short)r;
}
__device__ inline float bf2f(unsigned short h) {
  unsigned u = ((unsigned)h) << 16;
  return __builtin_bit_cast(float, u);
}
__device__ inline float2v pmax0(float2v a) {       // packed relu (v_pk_max_f32)
  float2v z = {0.f, 0.f};
  return __builtin_elementwise_max(a, z);
}
__device__ inline float rsum16(float16v cc) {      // sum of relu over 16 accum regs
  float2v s = pmax0(__builtin_shufflevector(cc, cc, 0, 1)) +
              pmax0(__builtin_shufflevector(cc, cc, 2, 3)) +
              pmax0(__builtin_shufflevector(cc, cc, 4, 5)) +
              pmax0(__builtin_shufflevector(cc, cc, 6, 7)) +
              pmax0(__builtin_shufflevector(cc, cc, 8, 9)) +
              pmax0(__builtin_shufflevector(cc, cc, 10, 11)) +
              pmax0(__builtin_shufflevector(cc, cc, 12, 13)) +
              pmax0(__builtin_shufflevector(cc, cc, 14, 15));
  return s[0] + s[1];
}

__global__ __launch_bounds__(256) void precompute_kernels(
    const float* __restrict__ kd,   // (3,3,1,8)
    const float* __restrict__ kp,   // (1,1,8,8)
    const float* __restrict__ k0,   // (5,5,1,8)
    const float* __restrict__ k1,   // (5,5,8,8)
    const float* __restrict__ k2,   // (3,3,8,16)
    const float* __restrict__ kx,   // (3,3,1,32)
    const float* __restrict__ ky,   // (3,3,1,32)
    const float* __restrict__ sm,   // (5,5,1,1)
    float* __restrict__ ws) {
  __shared__ float k9[648];
  __shared__ float k2s[72];
  __shared__ float kef[121];
  const int tid = threadIdx.x;

  for (int idx = tid; idx < 72; idx += 256) {
    int c = idx & 7, pq = idx >> 3;
    float s = 0.f;
    for (int c0 = 0; c0 < 8; ++c0) s = fmaf(kd[pq * 8 + c0], kp[c0 * 8 + c], s);
    ws[idx] = s;
  }
  for (int idx = tid; idx < 72; idx += 256) {
    int c1 = idx & 7, tv = idx >> 3;
    float s = 0.f;
    for (int c2 = 0; c2 < 16; ++c2) s += k2[(tv * 8 + c1) * 16 + c2];
    k2s[idx] = s;
  }
  for (int idx = tid; idx < 648; idx += 256) {
    int c1 = idx & 7;
    int ab = idx >> 3;
    int a = ab / 9, b = ab % 9;
    float s = 0.f;
    int plo = a > 4 ? a - 4 : 0, phi = a < 4 ? a : 4;
    int qlo = b > 4 ? b - 4 : 0, qhi = b < 4 ? b : 4;
    for (int p = plo; p <= phi; ++p)
      for (int q = qlo; q <= qhi; ++q) {
        int r = a - p, sx = b - q;
        const float* k0p = &k0[(p * 5 + q) * 8];
        const float* k1p = &k1[((r * 5 + sx) * 8) * 8 + c1];
        for (int c0 = 0; c0 < 8; ++c0) s = fmaf(k0p[c0], k1p[c0 * 8], s);
      }
    k9[idx] = s;
  }
  // F32-bank: grad filters as 32x32x16 A-frags (2 tiles: kx, ky)
  for (int idx = tid; idx < 1024; idx += 256) {
    int t = idx >> 9, ln = (idx >> 3) & 63, j = idx & 7;
    int k = (ln >> 5) * 8 + j;
    int ch = ln & 31;
    float v = 0.f;
    if (k < 9) v = (t == 0) ? kx[k * 32 + ch] : ky[k * 32 + ch];
    ((unsigned short*)ws)[F0 * 2 + idx] = f2bf(v);
  }
  // SMB-bank: smoother x-Toeplitz B-frags (bf16), one per y-tap a=0..4.
  for (int idx = tid; idx < 2560; idx += 256) {
    int a = idx >> 9, ln = (idx >> 3) & 63, j = idx & 7;
    int n = ln & 15;
    int k = (ln >> 4) * 8 + j;
    int d = k - n;
    float v = ((unsigned)d < 5u) ? sm[a * 5 + d] : 0.f;
    ((unsigned short*)ws)[SM0 * 2 + idx] = f2bf(v);
  }
  __syncthreads();
  for (int idx = tid; idx < 121; idx += 256) {
    int A = idx / 11, B = idx % 11;
    float s = 0.f;
    int tlo = A > 8 ? A - 8 : 0, thi = A < 2 ? A : 2;
    int vlo = B > 8 ? B - 8 : 0, vhi = B < 2 ? B : 2;
    for (int t = tlo; t <= thi; ++t)
      for (int v = vlo; v <= vhi; ++v) {
        int a = A - t, b = B - v;
        for (int c1 = 0; c1 < 8; ++c1)
          s = fmaf(k9[(a * 9 + b) * 8 + c1], k2s[(t * 3 + v) * 8 + c1], s);
      }
    ws[72 + idx] = s;
    kef[idx] = s;
  }
  __syncthreads();
  // KT2-bank: kappa x-Toeplitz B-frags (bf16), one per y-tap a=0..10.
  for (int idx = tid; idx < 5632; idx += 256) {
    int a = idx >> 9, ln = (idx >> 3) & 63, j = idx & 7;
    int n = ln & 15;
    int k = (ln >> 4) * 8 + j;
    int bb = k - n;
    float v = ((unsigned)bb < 11u) ? kef[a * 11 + bb] : 0.f;
    ((unsigned short*)ws)[KT0 * 2 + idx] = f2bf(v);
  }
}

// ---------------- fused kernel v11: MFMA smoother (phase 1c) ----------------
// R23: kernel is ISSUE-bound (R19/R22 TLP nulls; R18/R20 instr-cut wins). The
// biggest scalar pool left was the combine's 5x5 smoother (~160 instr/thread,
// scalar VALU). Now: 1b stores kappa*kk as bf16 (sk2, stride 72 = 9x16B), new
// phase 1c does the 5x5 smoother via x-Toeplitz MFMA (5 MFMA x 8 subtiles = 1
// subtile/wave), f32 results into si's storage (dead after 1a). Combine reads
// 1 LDS value per px. Smoother-path bf16 error ~1e-4 << 0.03125 floor (u-bf16
// in the 11x11 conv dominates, untouched).
__global__ __launch_bounds__(512) void fused(
    const float* __restrict__ u, const float* __restrict__ img,
    const float* __restrict__ kk, const float* __restrict__ ws,
    float* __restrict__ out) {
  // su2: u bf16 ROW-major [58 rows][88 stride]; staged rows by-7..by+39 (47),
  //      cols bx-7..bx+70 (78). Cols 78..87 zero-filled. Rows 47..57 + tail
  //      garbage: only read into discarded C rows. Stride 88 shorts = 11 x 16B
  //      (odd) -> conflict-free b128 reads.
  __shared__ alignas(16) unsigned short su2[58 * 88 + 16];
  __shared__ float si[36 * 71];           // image (ph 0-1a); reused as skn[32][68] f32 (ph 1c-2)
  __shared__ unsigned short sebf[34 * 68];// edges bf16, rows by-1..by+32, cols bx-1..bx+64 (66 used)
  __shared__ alignas(16) unsigned short sk2[36 * 72 + 16]; // kappa*kk bf16, stride 72 = 9x16B
                                          // cols 0..67 values, 68..71 + tail zeroed
  __shared__ alignas(16) float skf[72];   // keff_edge cached (broadcast reads)

  const int bx = blockIdx.x * TX, by = blockIdx.y * TY, b = blockIdx.z;
  const int tid = threadIdx.x;
  const float* ub = u + (size_t)b * HH * WW;
  const float* ib = img + (size_t)b * HH * WW;

  const int lane = tid & 63;
  const int wv   = tid >> 6;              // 0..7
  const int q    = lane >> 4;
  const int m    = lane & 15;

  // ---- phase 0: stage (row-major: coalesced global reads, conflict-free LDS) ----
  if (tid < 72) skf[tid] = ws[tid];
  for (int idx = tid; idx < 47 * 78; idx += 512) {
    int r = idx / 78, c = idx % 78;
    int gy = by - 7 + r, gx = bx - 7 + c;
    float v = 0.f;
    if ((unsigned)gy < HH && (unsigned)gx < WW) v = ub[gy * WW + gx];
    su2[r * 88 + c] = f2bf(v);
  }
  for (int idx = tid; idx < 58 * 5; idx += 512) {   // zero su2 cols 78..87
    int r = idx / 5, c2 = idx % 5;
    *reinterpret_cast<unsigned*>(&su2[r * 88 + 78 + c2 * 2]) = 0u;
  }
  for (int idx = tid; idx < 80; idx += 512) {       // zero sk2 cols 68..71 + tail
    if (idx < 72) {
      int r = idx >> 1, c2 = idx & 1;
      *reinterpret_cast<unsigned*>(&sk2[r * 72 + 68 + c2 * 2]) = 0u;
    } else {
      *reinterpret_cast<unsigned*>(&sk2[36 * 72 + (idx - 72) * 2]) = 0u;
    }
  }
  for (int idx = tid; idx < 36 * 70; idx += 512) {
    int i = idx / 70, j = idx % 70;
    int gy = by - 2 + i, gx = bx - 2 + j;
    float v = 0.f;
    if ((unsigned)gy < HH && (unsigned)gx < WW) v = ib[gy * WW + gx];
    si[i * 71 + j] = v;
  }
  __syncthreads();

  // ---- phase 1a: edges on 34 rows x 66 cols (strips of 4), packed channels ----
  for (int idx = tid; idx < 34 * 17; idx += 512) {
    int i = idx % 34, j0 = (idx / 34) * 4;
    float2v acc2[4][4];
    #pragma unroll
    for (int c2 = 0; c2 < 4; ++c2)
      #pragma unroll
      for (int t = 0; t < 4; ++t) acc2[c2][t] = (float2v){0.f, 0.f};
    #pragma unroll
    for (int p = 0; p < 3; ++p) {
      float r[6];
      #pragma unroll
      for (int t = 0; t < 6; ++t) r[t] = si[(i + p) * 71 + j0 + t];
      #pragma unroll
      for (int qq = 0; qq < 3; ++qq) {
        const float* wb = &skf[(p * 3 + qq) * 8];
        float2v w0 = *reinterpret_cast<const float2v*>(wb + 0);
        float2v w1 = *reinterpret_cast<const float2v*>(wb + 2);
        float2v w2 = *reinterpret_cast<const float2v*>(wb + 4);
        float2v w3 = *reinterpret_cast<const float2v*>(wb + 6);
        #pragma unroll
        for (int t = 0; t < 4; ++t) {
          float2v v2 = {r[qq + t], r[qq + t]};
          acc2[0][t] = acc2[0][t] + v2 * w0;
          acc2[1][t] = acc2[1][t] + v2 * w1;
          acc2[2][t] = acc2[2][t] + v2 * w2;
          acc2[3][t] = acc2[3][t] + v2 * w3;
        }
      }
    }
    int gy = by - 1 + i;
    #pragma unroll
    for (int t = 0; t < 4; ++t) {
      int j = j0 + t;
      if (j < 66) {
        int gx = bx - 1 + j;
        float val = 0.f;
        if ((unsigned)gy < HH && (unsigned)gx < WW) {
          float2v e2 = pmax0(acc2[0][t]) + pmax0(acc2[1][t]) +
                       pmax0(acc2[2][t]) + pmax0(acc2[3][t]);
          float e = e2[0] + e2[1];
          val = e / (1.f + e);
        }
        sebf[i * 68 + j] = f2bf(val);
      }
    }
  }

  // ---- phase 1b: kappa via swapped-operand Toeplitz MFMA, 3x5=15 subtiles ----
  {
    const unsigned short* KT = ((const unsigned short*)ws) + KT0 * 2;
    for (int s = wv; s < 15; s += 8) {
      int sty = s / 5, stx = s % 5;
      float4v acc = {0.f, 0.f, 0.f, 0.f};
      const unsigned short* arow = &su2[(sty * 16 + m) * 88 + stx * 16 + q * 8];
      #pragma unroll
      for (int a = 0; a < 11; ++a) {
        short8 bf = *reinterpret_cast<const short8*>(KT + (a * 64 + lane) * 8);
        short8 af = *reinterpret_cast<const short8*>(arow + a * 88);
        acc = __builtin_amdgcn_mfma_f32_16x16x32_bf16(af, bf, acc, 0, 0, 0);
      }
      #pragma unroll
      for (int i = 0; i < 4; ++i) {
        int rl = sty * 16 + q * 4 + i, cl = stx * 16 + m;
        if (rl < 36 && cl < 68) {
          int yy = by - 2 + rl, xx = bx - 2 + cl;
          float v = 0.f;
          if ((unsigned)yy < HH && (unsigned)xx < WW)
            v = acc[i] * kk[(size_t)yy * WW + xx];
          sk2[rl * 72 + cl] = f2bf(v);
        }
      }
    }
  }
  __syncthreads();

  // ---- phase 1c: 5x5 smoother via x-Toeplitz MFMA; skn reuses si storage ----
  // out[mm][nn] = sum_a sum_k sk2[sty16+mm+a][stx16+k] * sm[a][k-nn]
  // (k-nn in [0,4]; k<=19 live, k>=20 killed by B=0 -- A over-read stays finite
  //  via sk2 zero-fill cols 68..71 + tail; row m+a <= 35 staged.)
  {
    const unsigned short* SMB = ((const unsigned short*)ws) + SM0 * 2;
    const int sty = wv >> 2, stx = wv & 3;
    float4v acc = {0.f, 0.f, 0.f, 0.f};
    #pragma unroll
    for (int a = 0; a < 5; ++a) {
      short8 bf = *reinterpret_cast<const short8*>(SMB + (a * 64 + lane) * 8);
      short8 af = *reinterpret_cast<const short8*>(
          &sk2[(sty * 16 + m + a) * 72 + stx * 16 + q * 8]);
      acc = __builtin_amdgcn_mfma_f32_16x16x32_bf16(af, bf, acc, 0, 0, 0);
    }
    #pragma unroll
    for (int i = 0; i < 4; ++i)
      si[(sty * 16 + q * 4 + i) * 68 + stx * 16 + m] = acc[i];
  }
  __syncthreads();

  // ---- phase 2: grads via 32x32x16 MFMA + slim combine ----
  // Wave wv owns pixel rows wv*4 .. wv*4+3.
  {
    const unsigned short* F = ((const unsigned short*)ws) + F0 * 2;
    short8 afx = *reinterpret_cast<const short8*>(F + lane * 8);
    short8 afy = *reinterpret_cast<const short8*>(F + (64 + lane) * 8);

    const int c    = lane & 31;
    const int half = lane >> 5;
    const int R0   = wv * 4;              // wave's base pixel row

    #pragma unroll
    for (int h = 0; h < 2; ++h) {
      const int cl = h * 32 + c;            // pixel col (tile-local, 0..63)
      unsigned short W[9];
      #pragma unroll
      for (int d = 0; d < 3; ++d) {
        const unsigned short* rp = &sebf[(R0 + d) * 68 + cl];
        W[3 * d + 0] = rp[0]; W[3 * d + 1] = rp[1]; W[3 * d + 2] = rp[2];
      }

      float rxv[4], ryv[4];
      #pragma unroll
      for (int r = 0; r < 4; ++r) {
        short8 bv = (short8)0;
        if (half == 0) {
          #pragma unroll
          for (int j = 0; j < 8; ++j) bv[j] = (short)W[j];
        } else {
          bv[0] = (short)W[8];
        }

        // sequence through ONE accumulator: cx retires before cy allocates
        float16v cacc = {0.f, 0.f, 0.f, 0.f, 0.f, 0.f, 0.f, 0.f,
                         0.f, 0.f, 0.f, 0.f, 0.f, 0.f, 0.f, 0.f};
        cacc = __builtin_amdgcn_mfma_f32_32x32x16_bf16(afx, bv, cacc, 0, 0, 0);
        float rx = rsum16(cacc);
        cacc = (float16v){0.f, 0.f, 0.f, 0.f, 0.f, 0.f, 0.f, 0.f,
                          0.f, 0.f, 0.f, 0.f, 0.f, 0.f, 0.f, 0.f};
        cacc = __builtin_amdgcn_mfma_f32_32x32x16_bf16(afy, bv, cacc, 0, 0, 0);
        float ry = rsum16(cacc);

        rx += __shfl_xor(rx, 32);
        ry += __shfl_xor(ry, 32);
        rxv[r] = rx; ryv[r] = ry;

        if (r < 3) {
          #pragma unroll
          for (int t = 0; t < 6; ++t) W[t] = W[t + 3];
          const unsigned short* rp = &sebf[(R0 + r + 3) * 68 + cl];
          W[6] = rp[0]; W[7] = rp[1]; W[8] = rp[2];
        }
      }

      // combine: lane half -> rows B..B+1, B = R0 + 2*half, col cl
      {
        const int B = R0 + 2 * half;
        const int gx = bx + cl;

        float ucv[3];
        #pragma unroll
        for (int t = 0; t < 3; ++t) {
          int gy = by + B + t;
          ucv[t] = (gy < HH) ? ub[(size_t)gy * WW + gx] : 0.f;
        }

        #pragma unroll
        for (int rr = 0; rr < 2; ++rr) {
          const int oy = B + rr;
          const int gy = by + oy;
          float uc = ucv[rr];
          float ul = gx > 0 ? ub[(size_t)gy * WW + gx - 1] : 0.f;
          float ud = ucv[rr + 1];          // 0 at gy==HH-1 via guard above
          float ec = bf2f(sebf[(oy + 1) * 68 + cl + 1]);
          float kap = si[oy * 68 + cl];    // smoothed kappa (phase 1c)
          float xp = uc - ul;
          float yp = uc - ud;
          out[((size_t)b * HH + gy) * WW + gx] =
              uc + rxv[2 * half + rr] * xp + ryv[2 * half + rr] * yp + ec + kap;
        }
      }
    }
  }
}

// ---------------- Fallback: R3 monolith (used if ws too small) --------------
__global__ __launch_bounds__(256) void forcing_main(
    const float* __restrict__ u, const float* __restrict__ img,
    const float* __restrict__ kx, const float* __restrict__ ky,
    const float* __restrict__ sm, const float* __restrict__ kk,
    const float* __restrict__ ws, float* __restrict__ out) {
  __shared__ float su[46][48];
  __shared__ float si[36][37];
  __shared__ float se[34][35];
  __shared__ float sk[36][37];
  __shared__ float w_edge[72];
  __shared__ float w_kx[288];
  __shared__ float w_ky[288];
  __shared__ float w_k11[124];
  __shared__ float w_sm[28];

  const int bx = blockIdx.x * 32;
  const int by = blockIdx.y * 32;
  const int b  = blockIdx.z;
  const int tid = threadIdx.x;
  const float* ub = u   + (size_t)b * HH * WW;
  const float* ib = img + (size_t)b * HH * WW;

  for (int i = tid; i < 72; i += 256)  w_edge[i] = ws[i];
  for (int i = tid; i < 121; i += 256) w_k11[i]  = ws[72 + i];
  for (int i = tid; i < 288; i += 256) { w_kx[i] = kx[i]; w_ky[i] = ky[i]; }
  if (tid < 25) w_sm[tid] = sm[tid];

  for (int idx = tid; idx < 46 * 46; idx += 256) {
    int i = idx / 46, j = idx % 46;
    int gy = by - 7 + i, gx = bx - 7 + j;
    float v = 0.f;
    if ((unsigned)gy < HH && (unsigned)gx < WW) v = ub[gy * WW + gx];
    su[i][j] = v;
  }
  for (int idx = tid; idx < 36 * 36; idx += 256) {
    int i = idx / 36, j = idx % 36;
    int gy = by - 2 + i, gx = bx - 2 + j;
    float v = 0.f;
    if ((unsigned)gy < HH && (unsigned)gx < WW) v = ib[gy * WW + gx];
    si[i][j] = v;
  }
  __syncthreads();

  for (int idx = tid; idx < 34 * 9; idx += 256) {
    int i = idx / 9, j0 = (idx % 9) * 4;
    float acc[8][4];
    #pragma unroll
    for (int c = 0; c < 8; ++c)
      #pragma unroll
      for (int t = 0; t < 4; ++t) acc[c][t] = 0.f;
    #pragma unroll
    for (int p = 0; p < 3; ++p) {
      float r[6];
      #pragma unroll
      for (int t = 0; t < 6; ++t) r[t] = si[i + p][j0 + t];
      #pragma unroll
      for (int q = 0; q < 3; ++q) {
        const float4 w0 = *reinterpret_cast<const float4*>(&w_edge[(p * 3 + q) * 8]);
        const float4 w1 = *reinterpret_cast<const float4*>(&w_edge[(p * 3 + q) * 8 + 4]);
        #pragma unroll
        for (int t = 0; t < 4; ++t) {
          float v = r[q + t];
          acc[0][t] = fmaf(v, w0.x, acc[0][t]);
          acc[1][t] = fmaf(v, w0.y, acc[1][t]);
          acc[2][t] = fmaf(v, w0.z, acc[2][t]);
          acc[3][t] = fmaf(v, w0.w, acc[3][t]);
          acc[4][t] = fmaf(v, w1.x, acc[4][t]);
          acc[5][t] = fmaf(v, w1.y, acc[5][t]);
          acc[6][t] = fmaf(v, w1.z, acc[6][t]);
          acc[7][t] = fmaf(v, w1.w, acc[7][t]);
        }
      }
    }
    int gy = by - 1 + i;
    #pragma unroll
    for (int t = 0; t < 4; ++t) {
      int j = j0 + t;
      if (j < 34) {
        int gx = bx - 1 + j;
        float val = 0.f;
        if ((unsigned)gy < HH && (unsigned)gx < WW) {
          float e = 0.f;
          #pragma unroll
          for (int c = 0; c < 8; ++c) e += fmaxf(acc[c][t], 0.f);
          val = e / (1.f + e);
        }
        se[i][j] = val;
      }
    }
  }

  for (int idx = tid; idx < 36 * 9; idx += 256) {
    int i = idx / 9, js = (idx % 9) * 4;
    float o0 = 0.f, o1 = 0.f, o2 = 0.f, o3 = 0.f;
    #pragma unroll
    for (int A = 0; A < 11; ++A) {
      const float* row = &su[i + A][js];
      float4 v0 = *reinterpret_cast<const float4*>(row);
      float4 v1 = *reinterpret_cast<const float4*>(row + 4);
      float4 v2 = *reinterpret_cast<const float4*>(row + 8);
      float r[14] = {v0.x, v0.y, v0.z, v0.w, v1.x, v1.y, v1.z, v1.w,
                     v2.x, v2.y, v2.z, v2.w, row[12], row[13]};
      #pragma unroll
      for (int B2 = 0; B2 < 11; ++B2) {
        float w = w_k11[A * 11 + B2];
        o0 = fmaf(r[B2],     w, o0);
        o1 = fmaf(r[B2 + 1], w, o1);
        o2 = fmaf(r[B2 + 2], w, o2);
        o3 = fmaf(r[B2 + 3], w, o3);
      }
    }
    int gy = by - 2 + i;
    float o[4] = {o0, o1, o2, o3};
    #pragma unroll
    for (int t = 0; t < 4; ++t) {
      int gx = bx - 2 + js + t;
      float val = 0.f;
      if ((unsigned)gy < HH && (unsigned)gx < WW) val = o[t] * kk[gy * WW + gx];
      sk[i][js + t] = val;
    }
  }
  __syncthreads();

  {
    const int oy = tid >> 3;
    const int ox = (tid & 7) * 4;
    const int gy = by + oy;
    const int gx = bx + ox;

    float e[3][6];
    #pragma unroll
    for (int p = 0; p < 3; ++p)
      #pragma unroll
      for (int t = 0; t < 6; ++t) e[p][t] = se[oy + p][ox + t];

    const float4* wx4 = reinterpret_cast<const float4*>(w_kx);
    const float4* wy4 = reinterpret_cast<const float4*>(w_ky);

    float gxa[4] = {0.f, 0.f, 0.f, 0.f};
    float gya[4] = {0.f, 0.f, 0.f, 0.f};
    #pragma unroll
    for (int cq = 0; cq < 8; ++cq) {
      float sx[4][4], sy[4][4];
      #pragma unroll
      for (int cc = 0; cc < 4; ++cc)
        #pragma unroll
        for (int t = 0; t < 4; ++t) { sx[cc][t] = 0.f; sy[cc][t] = 0.f; }
      #pragma unroll
      for (int p = 0; p < 3; ++p)
        #pragma unroll
        for (int q = 0; q < 3; ++q) {
          float4 wx = wx4[(p * 3 + q) * 8 + cq];
          float4 wy = wy4[(p * 3 + q) * 8 + cq];
          #pragma unroll
          for (int t = 0; t < 4; ++t) {
            float evv = e[p][q + t];
            sx[0][t] = fmaf(evv, wx.x, sx[0][t]);
            sx[1][t] = fmaf(evv, wx.y, sx[1][t]);
            sx[2][t] = fmaf(evv, wx.z, sx[2][t]);
            sx[3][t] = fmaf(evv, wx.w, sx[3][t]);
            sy[0][t] = fmaf(evv, wy.x, sy[0][t]);
            sy[1][t] = fmaf(evv, wy.y, sy[1][t]);
            sy[2][t] = fmaf(evv, wy.z, sy[2][t]);
            sy[3][t] = fmaf(evv, wy.w, sy[3][t]);
          }
        }
      #pragma unroll
      for (int cc = 0; cc < 4; ++cc)
        #pragma unroll
        for (int t = 0; t < 4; ++t) {
          gxa[t] += fmaxf(sx[cc][t], 0.f);
          gya[t] += fmaxf(sy[cc][t], 0.f);
        }
    }

    float res[4];
    #pragma unroll
    for (int t = 0; t < 4; ++t) {
      float kap = 0.f;
      #pragma unroll
      for (int m = 0; m < 5; ++m)
        #pragma unroll
        for (int n = 0; n < 5; ++n)
          kap = fmaf(sk[oy + m][ox + t + n], w_sm[m * 5 + n], kap);

      float uc = su[oy + 7][ox + 7 + t];
      float xp = uc - su[oy + 7][ox + 6 + t];
      float yp = uc - su[oy + 8][ox + 7 + t];
      float ec = se[oy + 1][ox + 1 + t];
      res[t] = uc + gxa[t] * xp + gya[t] * yp + ec + kap;
    }

    float4 r4 = make_float4(res[0], res[1], res[2], res[3]);
    *reinterpret_cast<float4*>(&out[((size_t)b * HH + gy) * WW + gx]) = r4;
  }
}

extern "C" void kernel_launch(void* const* d_in, const int* in_sizes, int n_in,
                              void* d_out, int out_size, void* d_ws, size_t ws_size,
                              hipStream_t stream) {
  const float* u   = (const float*)d_in[0];
  const float* img = (const float*)d_in[1];
  const float* kx  = (const float*)d_in[2];
  const float* ky  = (const float*)d_in[3];
  const float* kd  = (const float*)d_in[4];
  const float* kp  = (const float*)d_in[5];
  const float* k0  = (const float*)d_in[6];
  const float* k1  = (const float*)d_in[7];
  const float* k2  = (const float*)d_in[8];
  const float* sm  = (const float*)d_in[9];
  const float* kk  = (const float*)d_in[10];
  float* out = (float*)d_out;
  float* ws  = (float*)d_ws;

  if (ws != nullptr && ws_size >= WS_NEEDED_BYTES) {
    precompute_kernels<<<1, 256, 0, stream>>>(kd, kp, k0, k1, k2, kx, ky, sm, ws);
    dim3 grid(WW / TX, HH / TY, BB);
    fused<<<grid, 512, 0, stream>>>(u, img, kk, ws, out);
  } else if (ws != nullptr && ws_size >= (size_t)4096 * 4) {
    precompute_kernels<<<1, 256, 0, stream>>>(kd, kp, k0, k1, k2, kx, ky, sm, ws);
    dim3 grid(WW / 32, HH / 32, BB);
    forcing_main<<<grid, 256, 0, stream>>>(u, img, kx, ky, sm, kk, ws, out);
  } else {
    // ws insufficient even for fallback banks -- should not occur; guard anyway
    dim3 grid(WW / 32, HH / 32, BB);
    forcing_main<<<grid, 256, 0, stream>>>(u, img, kx, ky, sm, kk, ws, out);
  }
}

// Round 8
// 125.277 us; speedup vs baseline: 1.0677x; 1.0677x over previous
//
#include <hip/hip_runtime.h>
#include <cstddef>

#define HH 512
#define WW 512
#define BB 8
#define TX 64
#define TY 32

// ws layout (floats):
//   [0..72)      keff_edge  (3*3)*8ch
//   [72..193)    Keff11     11*11
//   [256..1280)  F32-bank (grad filters, 32x32x16 A-frags): 2 tiles x 64 ln x 8 bf16
//                A_t[ch=ln&31][k=(ln>>5)*8+j] = (k<9) ? K_t[k*32+ch] : 0
//   [1280..4096) KT2-bank (kappa x-Toeplitz B-frags): 11 a x 64 lanes x 8 bf16
//                B_a[k=(ln>>4)*8+j][n=ln&15] = kef[a][k-n] if 0<=k-n<=10 else 0
#define F0    256
#define KT0   1280
#define WS_NEEDED_BYTES ((size_t)4096 * 4)

typedef __attribute__((ext_vector_type(8))) short short8;
typedef __attribute__((ext_vector_type(4))) float float4v;
typedef __attribute__((ext_vector_type(2))) float float2v;
typedef __attribute__((ext_vector_type(16))) float float16v;

__device__ inline unsigned short f2bf(float f) {   // fp32 -> bf16 RNE
  unsigned u = __builtin_bit_cast(unsigned, f);
  unsigned r = (u + 0x7FFFu + ((u >> 16) & 1u)) >> 16;
  return (unsigned short)r;
}
__device__ inline float bf2f(unsigned short h) {
  unsigned u = ((unsigned)h) << 16;
  return __builtin_bit_cast(float, u);
}
__device__ inline float2v pmax0(float2v a) {       // packed relu (v_pk_max_f32)
  float2v z = {0.f, 0.f};
  return __builtin_elementwise_max(a, z);
}
__device__ inline float rsum16(float16v cc) {      // sum of relu over 16 accum regs
  float2v s = pmax0(__builtin_shufflevector(cc, cc, 0, 1)) +
              pmax0(__builtin_shufflevector(cc, cc, 2, 3)) +
              pmax0(__builtin_shufflevector(cc, cc, 4, 5)) +
              pmax0(__builtin_shufflevector(cc, cc, 6, 7)) +
              pmax0(__builtin_shufflevector(cc, cc, 8, 9)) +
              pmax0(__builtin_shufflevector(cc, cc, 10, 11)) +
              pmax0(__builtin_shufflevector(cc, cc, 12, 13)) +
              pmax0(__builtin_shufflevector(cc, cc, 14, 15));
  return s[0] + s[1];
}

// R24: precompute rewritten -- it ran as ONE 256-thread workgroup with
// dependent GLOBAL loads in the k9 inner loop (400 loads/item), serialized
// before fused on the stream; an unmeasured 0-46us term hidden in the bench's
// constant ~87us. Now: k0 + transposed k1 staged in LDS (inner 8-dot = two
// contiguous b128 LDS reads), 1024 threads. Bit-identical math (same loop
// order / association).
__global__ __launch_bounds__(1024) void precompute_kernels(
    const float* __restrict__ kd,   // (3,3,1,8)
    const float* __restrict__ kp,   // (1,1,8,8)
    const float* __restrict__ k0,   // (5,5,1,8)
    const float* __restrict__ k1,   // (5,5,8,8)
    const float* __restrict__ k2,   // (3,3,8,16)
    const float* __restrict__ kx,   // (3,3,1,32)
    const float* __restrict__ ky,   // (3,3,1,32)
    float* __restrict__ ws) {
  __shared__ float sk0[200];    // k0 staged: [(p*5+q)*8 + c0]
  __shared__ float sk1t[1600];  // k1 transposed: [c1*200 + (r*5+sx)*8 + c0]
  __shared__ float k9[648];
  __shared__ float k2s[72];
  __shared__ float kef[121];
  const int tid = threadIdx.x;

  // stage k0 linear; k1 read linear (coalesced), write transposed
  for (int idx = tid; idx < 200; idx += 1024) sk0[idx] = k0[idx];
  for (int idx = tid; idx < 1600; idx += 1024) {
    int rs = idx >> 6, c0 = (idx >> 3) & 7, c1 = idx & 7;
    sk1t[c1 * 200 + rs * 8 + c0] = k1[idx];
  }
  // edge bank ws[0..72): (3,3)x8 effective depthwise*pointwise filters
  for (int idx = tid; idx < 72; idx += 1024) {
    int c = idx & 7, pq = idx >> 3;
    float s = 0.f;
    for (int c0 = 0; c0 < 8; ++c0) s = fmaf(kd[pq * 8 + c0], kp[c0 * 8 + c], s);
    ws[idx] = s;
  }
  // k2 channel-collapse: k2s[(tv)*8 + c1] = sum_c2 k2[...]
  for (int idx = tid; idx < 72; idx += 1024) {
    int c1 = idx & 7, tv = idx >> 3;
    float s = 0.f;
    for (int c2 = 0; c2 < 16; ++c2) s += k2[(tv * 8 + c1) * 16 + c2];
    k2s[idx] = s;
  }
  // F32-bank: grad filters as 32x32x16 A-frags (2 tiles: kx, ky)
  for (int idx = tid; idx < 1024; idx += 1024) {
    int t = idx >> 9, ln = (idx >> 3) & 63, j = idx & 7;
    int k = (ln >> 5) * 8 + j;
    int ch = ln & 31;
    float v = 0.f;
    if (k < 9) v = (t == 0) ? kx[k * 32 + ch] : ky[k * 32 + ch];
    ((unsigned short*)ws)[F0 * 2 + idx] = f2bf(v);
  }
  __syncthreads();

  // k9: 9x9 x 8ch composite of k0 (*) k1, all-LDS inner loops
  for (int idx = tid; idx < 648; idx += 1024) {
    int c1 = idx & 7;
    int ab = idx >> 3;
    int a = ab / 9, b = ab % 9;
    float s = 0.f;
    int plo = a > 4 ? a - 4 : 0, phi = a < 4 ? a : 4;
    int qlo = b > 4 ? b - 4 : 0, qhi = b < 4 ? b : 4;
    for (int p = plo; p <= phi; ++p)
      for (int q = qlo; q <= qhi; ++q) {
        int r = a - p, sx = b - q;
        const float* k0p = &sk0[(p * 5 + q) * 8];
        const float* k1p = &sk1t[c1 * 200 + (r * 5 + sx) * 8];
        #pragma unroll
        for (int c0 = 0; c0 < 8; ++c0) s = fmaf(k0p[c0], k1p[c0], s);
      }
    k9[idx] = s;
  }
  __syncthreads();

  // kef: 11x11 effective kappa kernel
  for (int idx = tid; idx < 121; idx += 1024) {
    int A = idx / 11, B = idx % 11;
    float s = 0.f;
    int tlo = A > 8 ? A - 8 : 0, thi = A < 2 ? A : 2;
    int vlo = B > 8 ? B - 8 : 0, vhi = B < 2 ? B : 2;
    for (int t = tlo; t <= thi; ++t)
      for (int v = vlo; v <= vhi; ++v) {
        int a = A - t, b = B - v;
        for (int c1 = 0; c1 < 8; ++c1)
          s = fmaf(k9[(a * 9 + b) * 8 + c1], k2s[(t * 3 + v) * 8 + c1], s);
      }
    ws[72 + idx] = s;
    kef[idx] = s;
  }
  __syncthreads();

  // KT2-bank: kappa x-Toeplitz B-frags (bf16), one per y-tap a=0..10.
  for (int idx = tid; idx < 5632; idx += 1024) {
    int a = idx >> 9, ln = (idx >> 3) & 63, j = idx & 7;
    int n = ln & 15;
    int k = (ln >> 4) * 8 + j;
    int bb = k - n;
    float v = ((unsigned)bb < 11u) ? kef[a * 11 + bb] : 0.f;
    ((unsigned short*)ws)[KT0 * 2 + idx] = f2bf(v);
  }
}

// ---------------- fused kernel v10 (reverted from v11): R22 version ---------
// R24: v11's MFMA smoother was a small regression (48.0 vs 46.5); revert to
// the proven v10: 64x32 tiles, 512 threads, 32x32x16 grad MFMA, scalar 5x5
// combine with f32 skp.
__global__ __launch_bounds__(512) void fused(
    const float* __restrict__ u, const float* __restrict__ img,
    const float* __restrict__ kk, const float* __restrict__ sm,
    const float* __restrict__ ws, float* __restrict__ out) {
  // su2: u bf16 ROW-major [58 rows][88 stride]; staged rows by-7..by+39 (47),
  //      cols bx-7..bx+70 (78). Cols 78..87 zero-filled. Rows 47..57 + tail
  //      garbage: only read into discarded C rows. Stride 88 shorts = 11 x 16B
  //      (odd) -> conflict-free b128 reads.
  __shared__ alignas(16) unsigned short su2[58 * 88 + 16];
  __shared__ float si[36 * 71];           // image, rows by-2..by+33, cols bx-2..bx+67
  __shared__ unsigned short sebf[34 * 68];// edges bf16, rows by-1..by+32, cols bx-1..bx+64 (66 used)
  __shared__ float skp[36 * 69];          // kappa*kk, rows by-2..by+33, cols bx-2..bx+65 (68 used)
  __shared__ alignas(16) float skf[72];   // keff_edge cached (broadcast reads)

  const int bx = blockIdx.x * TX, by = blockIdx.y * TY, b = blockIdx.z;
  const int tid = threadIdx.x;
  const float* ub = u + (size_t)b * HH * WW;
  const float* ib = img + (size_t)b * HH * WW;

  const int lane = tid & 63;
  const int wv   = tid >> 6;              // 0..7
  const int q    = lane >> 4;
  const int m    = lane & 15;

  // ---- phase 0: stage (row-major: coalesced global reads, conflict-free LDS) ----
  if (tid < 72) skf[tid] = ws[tid];
  for (int idx = tid; idx < 47 * 78; idx += 512) {
    int r = idx / 78, c = idx % 78;
    int gy = by - 7 + r, gx = bx - 7 + c;
    float v = 0.f;
    if ((unsigned)gy < HH && (unsigned)gx < WW) v = ub[gy * WW + gx];
    su2[r * 88 + c] = f2bf(v);
  }
  for (int idx = tid; idx < 58 * 5; idx += 512) {   // zero cols 78..87, all 58 rows
    int r = idx / 5, c2 = idx % 5;
    *reinterpret_cast<unsigned*>(&su2[r * 88 + 78 + c2 * 2]) = 0u;
  }
  for (int idx = tid; idx < 36 * 70; idx += 512) {
    int i = idx / 70, j = idx % 70;
    int gy = by - 2 + i, gx = bx - 2 + j;
    float v = 0.f;
    if ((unsigned)gy < HH && (unsigned)gx < WW) v = ib[gy * WW + gx];
    si[i * 71 + j] = v;
  }
  __syncthreads();

  // ---- phase 1a: edges on 34 rows x 66 cols (strips of 4), packed channels ----
  for (int idx = tid; idx < 34 * 17; idx += 512) {
    int i = idx % 34, j0 = (idx / 34) * 4;
    float2v acc2[4][4];
    #pragma unroll
    for (int c2 = 0; c2 < 4; ++c2)
      #pragma unroll
      for (int t = 0; t < 4; ++t) acc2[c2][t] = (float2v){0.f, 0.f};
    #pragma unroll
    for (int p = 0; p < 3; ++p) {
      float r[6];
      #pragma unroll
      for (int t = 0; t < 6; ++t) r[t] = si[(i + p) * 71 + j0 + t];
      #pragma unroll
      for (int qq = 0; qq < 3; ++qq) {
        const float* wb = &skf[(p * 3 + qq) * 8];
        float2v w0 = *reinterpret_cast<const float2v*>(wb + 0);
        float2v w1 = *reinterpret_cast<const float2v*>(wb + 2);
        float2v w2 = *reinterpret_cast<const float2v*>(wb + 4);
        float2v w3 = *reinterpret_cast<const float2v*>(wb + 6);
        #pragma unroll
        for (int t = 0; t < 4; ++t) {
          float2v v2 = {r[qq + t], r[qq + t]};
          acc2[0][t] = acc2[0][t] + v2 * w0;
          acc2[1][t] = acc2[1][t] + v2 * w1;
          acc2[2][t] = acc2[2][t] + v2 * w2;
          acc2[3][t] = acc2[3][t] + v2 * w3;
        }
      }
    }
    int gy = by - 1 + i;
    #pragma unroll
    for (int t = 0; t < 4; ++t) {
      int j = j0 + t;
      if (j < 66) {
        int gx = bx - 1 + j;
        float val = 0.f;
        if ((unsigned)gy < HH && (unsigned)gx < WW) {
          float2v e2 = pmax0(acc2[0][t]) + pmax0(acc2[1][t]) +
                       pmax0(acc2[2][t]) + pmax0(acc2[3][t]);
          float e = e2[0] + e2[1];
          val = e / (1.f + e);
        }
        sebf[i * 68 + j] = f2bf(val);
      }
    }
  }

  // ---- phase 1b: kappa via swapped-operand Toeplitz MFMA, 3x5=15 subtiles ----
  {
    const unsigned short* KT = ((const unsigned short*)ws) + KT0 * 2;
    for (int s = wv; s < 15; s += 8) {
      int sty = s / 5, stx = s % 5;
      float4v acc = {0.f, 0.f, 0.f, 0.f};
      const unsigned short* arow = &su2[(sty * 16 + m) * 88 + stx * 16 + q * 8];
      #pragma unroll
      for (int a = 0; a < 11; ++a) {
        short8 bf = *reinterpret_cast<const short8*>(KT + (a * 64 + lane) * 8);
        short8 af = *reinterpret_cast<const short8*>(arow + a * 88);
        acc = __builtin_amdgcn_mfma_f32_16x16x32_bf16(af, bf, acc, 0, 0, 0);
      }
      #pragma unroll
      for (int i = 0; i < 4; ++i) {
        int rl = sty * 16 + q * 4 + i, cl = stx * 16 + m;
        if (rl < 36 && cl < 68) {
          int yy = by - 2 + rl, xx = bx - 2 + cl;
          float v = 0.f;
          if ((unsigned)yy < HH && (unsigned)xx < WW)
            v = acc[i] * kk[(size_t)yy * WW + xx];
          skp[rl * 69 + cl] = v;
        }
      }
    }
  }
  __syncthreads();

  // ---- phase 2: grads via 32x32x16 MFMA + split combine ----
  // Wave wv owns pixel rows wv*4 .. wv*4+3.
  {
    const unsigned short* F = ((const unsigned short*)ws) + F0 * 2;
    short8 afx = *reinterpret_cast<const short8*>(F + lane * 8);
    short8 afy = *reinterpret_cast<const short8*>(F + (64 + lane) * 8);

    const int c    = lane & 31;
    const int half = lane >> 5;
    const int R0   = wv * 4;              // wave's base pixel row

    #pragma unroll
    for (int h = 0; h < 2; ++h) {
      const int cl = h * 32 + c;            // pixel col (tile-local, 0..63)
      unsigned short W[9];
      #pragma unroll
      for (int d = 0; d < 3; ++d) {
        const unsigned short* rp = &sebf[(R0 + d) * 68 + cl];
        W[3 * d + 0] = rp[0]; W[3 * d + 1] = rp[1]; W[3 * d + 2] = rp[2];
      }

      float rxv[4], ryv[4];
      #pragma unroll
      for (int r = 0; r < 4; ++r) {
        short8 bv = (short8)0;
        if (half == 0) {
          #pragma unroll
          for (int j = 0; j < 8; ++j) bv[j] = (short)W[j];
        } else {
          bv[0] = (short)W[8];
        }

        // sequence through ONE accumulator: cx retires before cy allocates
        float16v cacc = {0.f, 0.f, 0.f, 0.f, 0.f, 0.f, 0.f, 0.f,
                         0.f, 0.f, 0.f, 0.f, 0.f, 0.f, 0.f, 0.f};
        cacc = __builtin_amdgcn_mfma_f32_32x32x16_bf16(afx, bv, cacc, 0, 0, 0);
        float rx = rsum16(cacc);
        cacc = (float16v){0.f, 0.f, 0.f, 0.f, 0.f, 0.f, 0.f, 0.f,
                          0.f, 0.f, 0.f, 0.f, 0.f, 0.f, 0.f, 0.f};
        cacc = __builtin_amdgcn_mfma_f32_32x32x16_bf16(afy, bv, cacc, 0, 0, 0);
        float ry = rsum16(cacc);

        rx += __shfl_xor(rx, 32);
        ry += __shfl_xor(ry, 32);
        rxv[r] = rx; ryv[r] = ry;

        if (r < 3) {
          #pragma unroll
          for (int t = 0; t < 6; ++t) W[t] = W[t + 3];
          const unsigned short* rp = &sebf[(R0 + r + 3) * 68 + cl];
          W[6] = rp[0]; W[7] = rp[1]; W[8] = rp[2];
        }
      }

      // combine: lane half -> rows B..B+1, B = R0 + 2*half, col cl
      {
        const int B = R0 + 2 * half;
        const int gx = bx + cl;

        float kap[2] = {0.f, 0.f};
        #pragma unroll
        for (int ii = 0; ii < 6; ++ii) {
          float rowv[5];
          #pragma unroll
          for (int n = 0; n < 5; ++n) rowv[n] = skp[(B + ii) * 69 + cl + n];
          #pragma unroll
          for (int rr = 0; rr < 2; ++rr) {
            const int m5 = ii - rr;
            if (m5 >= 0 && m5 < 5) {
              #pragma unroll
              for (int n = 0; n < 5; ++n)
                kap[rr] = fmaf(rowv[n], sm[m5 * 5 + n], kap[rr]);
            }
          }
        }

        float ucv[3];
        #pragma unroll
        for (int t = 0; t < 3; ++t) {
          int gy = by + B + t;
          ucv[t] = (gy < HH) ? ub[(size_t)gy * WW + gx] : 0.f;
        }

        #pragma unroll
        for (int rr = 0; rr < 2; ++rr) {
          const int oy = B + rr;
          const int gy = by + oy;
          float uc = ucv[rr];
          float ul = gx > 0 ? ub[(size_t)gy * WW + gx - 1] : 0.f;
          float ud = ucv[rr + 1];          // 0 at gy==HH-1 via guard above
          float ec = bf2f(sebf[(oy + 1) * 68 + cl + 1]);
          float xp = uc - ul;
          float yp = uc - ud;
          out[((size_t)b * HH + gy) * WW + gx] =
              uc + rxv[2 * half + rr] * xp + ryv[2 * half + rr] * yp + ec + kap[rr];
        }
      }
    }
  }
}

// ---------------- Fallback: R3 monolith (used if ws too small) --------------
__global__ __launch_bounds__(256) void forcing_main(
    const float* __restrict__ u, const float* __restrict__ img,
    const float* __restrict__ kx, const float* __restrict__ ky,
    const float* __restrict__ sm, const float* __restrict__ kk,
    const float* __restrict__ ws, float* __restrict__ out) {
  __shared__ float su[46][48];
  __shared__ float si[36][37];
  __shared__ float se[34][35];
  __shared__ float sk[36][37];
  __shared__ float w_edge[72];
  __shared__ float w_kx[288];
  __shared__ float w_ky[288];
  __shared__ float w_k11[124];
  __shared__ float w_sm[28];

  const int bx = blockIdx.x * 32;
  const int by = blockIdx.y * 32;
  const int b  = blockIdx.z;
  const int tid = threadIdx.x;
  const float* ub = u   + (size_t)b * HH * WW;
  const float* ib = img + (size_t)b * HH * WW;

  for (int i = tid; i < 72; i += 256)  w_edge[i] = ws[i];
  for (int i = tid; i < 121; i += 256) w_k11[i]  = ws[72 + i];
  for (int i = tid; i < 288; i += 256) { w_kx[i] = kx[i]; w_ky[i] = ky[i]; }
  if (tid < 25) w_sm[tid] = sm[tid];

  for (int idx = tid; idx < 46 * 46; idx += 256) {
    int i = idx / 46, j = idx % 46;
    int gy = by - 7 + i, gx = bx - 7 + j;
    float v = 0.f;
    if ((unsigned)gy < HH && (unsigned)gx < WW) v = ub[gy * WW + gx];
    su[i][j] = v;
  }
  for (int idx = tid; idx < 36 * 36; idx += 256) {
    int i = idx / 36, j = idx % 36;
    int gy = by - 2 + i, gx = bx - 2 + j;
    float v = 0.f;
    if ((unsigned)gy < HH && (unsigned)gx < WW) v = ib[gy * WW + gx];
    si[i][j] = v;
  }
  __syncthreads();

  for (int idx = tid; idx < 34 * 9; idx += 256) {
    int i = idx / 9, j0 = (idx % 9) * 4;
    float acc[8][4];
    #pragma unroll
    for (int c = 0; c < 8; ++c)
      #pragma unroll
      for (int t = 0; t < 4; ++t) acc[c][t] = 0.f;
    #pragma unroll
    for (int p = 0; p < 3; ++p) {
      float r[6];
      #pragma unroll
      for (int t = 0; t < 6; ++t) r[t] = si[i + p][j0 + t];
      #pragma unroll
      for (int q = 0; q < 3; ++q) {
        const float4 w0 = *reinterpret_cast<const float4*>(&w_edge[(p * 3 + q) * 8]);
        const float4 w1 = *reinterpret_cast<const float4*>(&w_edge[(p * 3 + q) * 8 + 4]);
        #pragma unroll
        for (int t = 0; t < 4; ++t) {
          float v = r[q + t];
          acc[0][t] = fmaf(v, w0.x, acc[0][t]);
          acc[1][t] = fmaf(v, w0.y, acc[1][t]);
          acc[2][t] = fmaf(v, w0.z, acc[2][t]);
          acc[3][t] = fmaf(v, w0.w, acc[3][t]);
          acc[4][t] = fmaf(v, w1.x, acc[4][t]);
          acc[5][t] = fmaf(v, w1.y, acc[5][t]);
          acc[6][t] = fmaf(v, w1.z, acc[6][t]);
          acc[7][t] = fmaf(v, w1.w, acc[7][t]);
        }
      }
    }
    int gy = by - 1 + i;
    #pragma unroll
    for (int t = 0; t < 4; ++t) {
      int j = j0 + t;
      if (j < 34) {
        int gx = bx - 1 + j;
        float val = 0.f;
        if ((unsigned)gy < HH && (unsigned)gx < WW) {
          float e = 0.f;
          #pragma unroll
          for (int c = 0; c < 8; ++c) e += fmaxf(acc[c][t], 0.f);
          val = e / (1.f + e);
        }
        se[i][j] = val;
      }
    }
  }

  for (int idx = tid; idx < 36 * 9; idx += 256) {
    int i = idx / 9, js = (idx % 9) * 4;
    float o0 = 0.f, o1 = 0.f, o2 = 0.f, o3 = 0.f;
    #pragma unroll
    for (int A = 0; A < 11; ++A) {
      const float* row = &su[i + A][js];
      float4 v0 = *reinterpret_cast<const float4*>(row);
      float4 v1 = *reinterpret_cast<const float4*>(row + 4);
      float4 v2 = *reinterpret_cast<const float4*>(row + 8);
      float r[14] = {v0.x, v0.y, v0.z, v0.w, v1.x, v1.y, v1.z, v1.w,
                     v2.x, v2.y, v2.z, v2.w, row[12], row[13]};
      #pragma unroll
      for (int B2 = 0; B2 < 11; ++B2) {
        float w = w_k11[A * 11 + B2];
        o0 = fmaf(r[B2],     w, o0);
        o1 = fmaf(r[B2 + 1], w, o1);
        o2 = fmaf(r[B2 + 2], w, o2);
        o3 = fmaf(r[B2 + 3], w, o3);
      }
    }
    int gy = by - 2 + i;
    float o[4] = {o0, o1, o2, o3};
    #pragma unroll
    for (int t = 0; t < 4; ++t) {
      int gx = bx - 2 + js + t;
      float val = 0.f;
      if ((unsigned)gy < HH && (unsigned)gx < WW) val = o[t] * kk[gy * WW + gx];
      sk[i][js + t] = val;
    }
  }
  __syncthreads();

  {
    const int oy = tid >> 3;
    const int ox = (tid & 7) * 4;
    const int gy = by + oy;
    const int gx = bx + ox;

    float e[3][6];
    #pragma unroll
    for (int p = 0; p < 3; ++p)
      #pragma unroll
      for (int t = 0; t < 6; ++t) e[p][t] = se[oy + p][ox + t];

    const float4* wx4 = reinterpret_cast<const float4*>(w_kx);
    const float4* wy4 = reinterpret_cast<const float4*>(w_ky);

    float gxa[4] = {0.f, 0.f, 0.f, 0.f};
    float gya[4] = {0.f, 0.f, 0.f, 0.f};
    #pragma unroll
    for (int cq = 0; cq < 8; ++cq) {
      float sx[4][4], sy[4][4];
      #pragma unroll
      for (int cc = 0; cc < 4; ++cc)
        #pragma unroll
        for (int t = 0; t < 4; ++t) { sx[cc][t] = 0.f; sy[cc][t] = 0.f; }
      #pragma unroll
      for (int p = 0; p < 3; ++p)
        #pragma unroll
        for (int q = 0; q < 3; ++q) {
          float4 wx = wx4[(p * 3 + q) * 8 + cq];
          float4 wy = wy4[(p * 3 + q) * 8 + cq];
          #pragma unroll
          for (int t = 0; t < 4; ++t) {
            float evv = e[p][q + t];
            sx[0][t] = fmaf(evv, wx.x, sx[0][t]);
            sx[1][t] = fmaf(evv, wx.y, sx[1][t]);
            sx[2][t] = fmaf(evv, wx.z, sx[2][t]);
            sx[3][t] = fmaf(evv, wx.w, sx[3][t]);
            sy[0][t] = fmaf(evv, wy.x, sy[0][t]);
            sy[1][t] = fmaf(evv, wy.y, sy[1][t]);
            sy[2][t] = fmaf(evv, wy.z, sy[2][t]);
            sy[3][t] = fmaf(evv, wy.w, sy[3][t]);
          }
        }
      #pragma unroll
      for (int cc = 0; cc < 4; ++cc)
        #pragma unroll
        for (int t = 0; t < 4; ++t) {
          gxa[t] += fmaxf(sx[cc][t], 0.f);
          gya[t] += fmaxf(sy[cc][t], 0.f);
        }
    }

    float res[4];
    #pragma unroll
    for (int t = 0; t < 4; ++t) {
      float kap = 0.f;
      #pragma unroll
      for (int m = 0; m < 5; ++m)
        #pragma unroll
        for (int n = 0; n < 5; ++n)
          kap = fmaf(sk[oy + m][ox + t + n], w_sm[m * 5 + n], kap);

      float uc = su[oy + 7][ox + 7 + t];
      float xp = uc - su[oy + 7][ox + 6 + t];
      float yp = uc - su[oy + 8][ox + 7 + t];
      float ec = se[oy + 1][ox + 1 + t];
      res[t] = uc + gxa[t] * xp + gya[t] * yp + ec + kap;
    }

    float4 r4 = make_float4(res[0], res[1], res[2], res[3]);
    *reinterpret_cast<float4*>(&out[((size_t)b * HH + gy) * WW + gx]) = r4;
  }
}

extern "C" void kernel_launch(void* const* d_in, const int* in_sizes, int n_in,
                              void* d_out, int out_size, void* d_ws, size_t ws_size,
                              hipStream_t stream) {
  const float* u   = (const float*)d_in[0];
  const float* img = (const float*)d_in[1];
  const float* kx  = (const float*)d_in[2];
  const float* ky  = (const float*)d_in[3];
  const float* kd  = (const float*)d_in[4];
  const float* kp  = (const float*)d_in[5];
  const float* k0  = (const float*)d_in[6];
  const float* k1  = (const float*)d_in[7];
  const float* k2  = (const float*)d_in[8];
  const float* sm  = (const float*)d_in[9];
  const float* kk  = (const float*)d_in[10];
  float* out = (float*)d_out;
  float* ws  = (float*)d_ws;

  precompute_kernels<<<1, 1024, 0, stream>>>(kd, kp, k0, k1, k2, kx, ky, ws);
  if (ws != nullptr && ws_size >= WS_NEEDED_BYTES) {
    dim3 grid(WW / TX, HH / TY, BB);
    fused<<<grid, 512, 0, stream>>>(u, img, kk, sm, ws, out);
  } else {
    dim3 grid(WW / 32, HH / 32, BB);
    forcing_main<<<grid, 256, 0, stream>>>(u, img, kx, ky, sm, kk, ws, out);
  }
}

// Round 9
// 123.902 us; speedup vs baseline: 1.0795x; 1.0111x over previous
//
#include <hip/hip_runtime.h>
#include <cstddef>

#define HH 512
#define WW 512
#define BB 8
#define TX 64
#define TY 32

// ws layout (floats):
//   [0..72)      keff_edge  (3*3)*8ch
//   [72..193)    Keff11     11*11
//   [256..1280)  F32-bank (grad filters, 32x32x16 A-frags): 2 tiles x 64 ln x 8 bf16
//                A_t[ch=ln&31][k=(ln>>5)*8+j] = (k<9) ? K_t[k*32+ch] : 0
//   [1280..4096) KT2-bank (kappa x-Toeplitz B-frags): 11 a x 64 lanes x 8 bf16
//                R25: B_a[k][n] = kef[a][k-n-1] if 0<=k-n-1<=10 else 0
//                (column base shifted: su2 staged from bx-8 for 16B-aligned
//                 float4 loads; gx-xx = k-n-6 = b-5 => b = k-n-1)
#define F0    256
#define KT0   1280
#define WS_NEEDED_BYTES ((size_t)4096 * 4)

typedef __attribute__((ext_vector_type(8))) short short8;
typedef __attribute__((ext_vector_type(4))) float float4v;
typedef __attribute__((ext_vector_type(2))) float float2v;
typedef __attribute__((ext_vector_type(16))) float float16v;

__device__ inline unsigned short f2bf(float f) {   // fp32 -> bf16 RNE
  unsigned u = __builtin_bit_cast(unsigned, f);
  unsigned r = (u + 0x7FFFu + ((u >> 16) & 1u)) >> 16;
  return (unsigned short)r;
}
__device__ inline float bf2f(unsigned short h) {
  unsigned u = ((unsigned)h) << 16;
  return __builtin_bit_cast(float, u);
}
__device__ inline float2v pmax0(float2v a) {       // packed relu (v_pk_max_f32)
  float2v z = {0.f, 0.f};
  return __builtin_elementwise_max(a, z);
}
__device__ inline float rsum16(float16v cc) {      // sum of relu over 16 accum regs
  float2v s = pmax0(__builtin_shufflevector(cc, cc, 0, 1)) +
              pmax0(__builtin_shufflevector(cc, cc, 2, 3)) +
              pmax0(__builtin_shufflevector(cc, cc, 4, 5)) +
              pmax0(__builtin_shufflevector(cc, cc, 6, 7)) +
              pmax0(__builtin_shufflevector(cc, cc, 8, 9)) +
              pmax0(__builtin_shufflevector(cc, cc, 10, 11)) +
              pmax0(__builtin_shufflevector(cc, cc, 12, 13)) +
              pmax0(__builtin_shufflevector(cc, cc, 14, 15));
  return s[0] + s[1];
}

// R24 precompute: k0 + transposed k1 staged in LDS, 1024 threads.
// R25: KT2 bank emits kef[a][k-n-1] (column-base shift, see ws layout note).
__global__ __launch_bounds__(1024) void precompute_kernels(
    const float* __restrict__ kd,   // (3,3,1,8)
    const float* __restrict__ kp,   // (1,1,8,8)
    const float* __restrict__ k0,   // (5,5,1,8)
    const float* __restrict__ k1,   // (5,5,8,8)
    const float* __restrict__ k2,   // (3,3,8,16)
    const float* __restrict__ kx,   // (3,3,1,32)
    const float* __restrict__ ky,   // (3,3,1,32)
    float* __restrict__ ws) {
  __shared__ float sk0[200];    // k0 staged: [(p*5+q)*8 + c0]
  __shared__ float sk1t[1600];  // k1 transposed: [c1*200 + (r*5+sx)*8 + c0]
  __shared__ float k9[648];
  __shared__ float k2s[72];
  __shared__ float kef[121];
  const int tid = threadIdx.x;

  // stage k0 linear; k1 read linear (coalesced), write transposed
  for (int idx = tid; idx < 200; idx += 1024) sk0[idx] = k0[idx];
  for (int idx = tid; idx < 1600; idx += 1024) {
    int rs = idx >> 6, c0 = (idx >> 3) & 7, c1 = idx & 7;
    sk1t[c1 * 200 + rs * 8 + c0] = k1[idx];
  }
  // edge bank ws[0..72): (3,3)x8 effective depthwise*pointwise filters
  for (int idx = tid; idx < 72; idx += 1024) {
    int c = idx & 7, pq = idx >> 3;
    float s = 0.f;
    for (int c0 = 0; c0 < 8; ++c0) s = fmaf(kd[pq * 8 + c0], kp[c0 * 8 + c], s);
    ws[idx] = s;
  }
  // k2 channel-collapse: k2s[(tv)*8 + c1] = sum_c2 k2[...]
  for (int idx = tid; idx < 72; idx += 1024) {
    int c1 = idx & 7, tv = idx >> 3;
    float s = 0.f;
    for (int c2 = 0; c2 < 16; ++c2) s += k2[(tv * 8 + c1) * 16 + c2];
    k2s[idx] = s;
  }
  // F32-bank: grad filters as 32x32x16 A-frags (2 tiles: kx, ky)
  for (int idx = tid; idx < 1024; idx += 1024) {
    int t = idx >> 9, ln = (idx >> 3) & 63, j = idx & 7;
    int k = (ln >> 5) * 8 + j;
    int ch = ln & 31;
    float v = 0.f;
    if (k < 9) v = (t == 0) ? kx[k * 32 + ch] : ky[k * 32 + ch];
    ((unsigned short*)ws)[F0 * 2 + idx] = f2bf(v);
  }
  __syncthreads();

  // k9: 9x9 x 8ch composite of k0 (*) k1, all-LDS inner loops
  for (int idx = tid; idx < 648; idx += 1024) {
    int c1 = idx & 7;
    int ab = idx >> 3;
    int a = ab / 9, b = ab % 9;
    float s = 0.f;
    int plo = a > 4 ? a - 4 : 0, phi = a < 4 ? a : 4;
    int qlo = b > 4 ? b - 4 : 0, qhi = b < 4 ? b : 4;
    for (int p = plo; p <= phi; ++p)
      for (int q = qlo; q <= qhi; ++q) {
        int r = a - p, sx = b - q;
        const float* k0p = &sk0[(p * 5 + q) * 8];
        const float* k1p = &sk1t[c1 * 200 + (r * 5 + sx) * 8];
        #pragma unroll
        for (int c0 = 0; c0 < 8; ++c0) s = fmaf(k0p[c0], k1p[c0], s);
      }
    k9[idx] = s;
  }
  __syncthreads();

  // kef: 11x11 effective kappa kernel
  for (int idx = tid; idx < 121; idx += 1024) {
    int A = idx / 11, B = idx % 11;
    float s = 0.f;
    int tlo = A > 8 ? A - 8 : 0, thi = A < 2 ? A : 2;
    int vlo = B > 8 ? B - 8 : 0, vhi = B < 2 ? B : 2;
    for (int t = tlo; t <= thi; ++t)
      for (int v = vlo; v <= vhi; ++v) {
        int a = A - t, b = B - v;
        for (int c1 = 0; c1 < 8; ++c1)
          s = fmaf(k9[(a * 9 + b) * 8 + c1], k2s[(t * 3 + v) * 8 + c1], s);
      }
    ws[72 + idx] = s;
    kef[idx] = s;
  }
  __syncthreads();

  // KT2-bank: kappa x-Toeplitz B-frags (bf16), one per y-tap a=0..10.
  // R25: shifted index (k-n-1) for the bx-8 staging base.
  for (int idx = tid; idx < 5632; idx += 1024) {
    int a = idx >> 9, ln = (idx >> 3) & 63, j = idx & 7;
    int n = ln & 15;
    int k = (ln >> 4) * 8 + j;
    int bb = k - n - 1;
    float v = ((unsigned)bb < 11u) ? kef[a * 11 + bb] : 0.f;
    ((unsigned short*)ws)[KT0 * 2 + idx] = f2bf(v);
  }
}

// ---------------- fused kernel v12: vectorized staging ----------------------
// R25: phase 0 was the largest untouched instruction pool (~180 instr/thread:
// 3666 scalar u loads + f2bf + ds_write, 2520 scalar image loads). Now:
// su2 staged from an aligned 80-col window (bx-8..bx+71, 16B-aligned since
// bx%64==0) via float4 loads -> manual-RNE f2bf x4 -> one ds_write_b64 per
// group (940 groups). Column shift absorbed by the KT2 bank (k-n-1). si via
// float2 loads (1260 groups). Same bytes moved, ~2-4x fewer memory instrs.
__global__ __launch_bounds__(512) void fused(
    const float* __restrict__ u, const float* __restrict__ img,
    const float* __restrict__ kk, const float* __restrict__ sm,
    const float* __restrict__ ws, float* __restrict__ out) {
  // su2: u bf16 ROW-major [58 rows][88 stride]; staged rows by-7..by+39 (47),
  //      cols bx-8..bx+71 (80). Cols 80..87 zero-filled (read through B-zeros
  //      by live C elements -> must be finite). Rows 47..57 + tail garbage:
  //      only read into discarded C rows. Stride 88 shorts = 11 x 16B (odd)
  //      -> conflict-free b128 reads. Live-output reads reach col <= 78.
  __shared__ alignas(16) unsigned short su2[58 * 88 + 16];
  __shared__ float si[36 * 71];           // image, rows by-2..by+33, cols bx-2..bx+67
  __shared__ unsigned short sebf[34 * 68];// edges bf16, rows by-1..by+32, cols bx-1..bx+64 (66 used)
  __shared__ float skp[36 * 69];          // kappa*kk, rows by-2..by+33, cols bx-2..bx+65 (68 used)
  __shared__ alignas(16) float skf[72];   // keff_edge cached (broadcast reads)

  const int bx = blockIdx.x * TX, by = blockIdx.y * TY, b = blockIdx.z;
  const int tid = threadIdx.x;
  const float* ub = u + (size_t)b * HH * WW;
  const float* ib = img + (size_t)b * HH * WW;

  const int lane = tid & 63;
  const int wv   = tid >> 6;              // 0..7
  const int q    = lane >> 4;
  const int m    = lane & 15;

  // ---- phase 0: stage (vectorized: float4 u, float2 image) ----
  if (tid < 72) skf[tid] = ws[tid];
  // su2: 47 rows x 20 float4-groups, window cols bx-8..bx+71 (16B-aligned)
  for (int idx = tid; idx < 47 * 20; idx += 512) {
    int r = idx / 20, g = idx % 20;
    int gy = by - 7 + r;
    int gx0 = bx - 8 + g * 4;
    float4 v = make_float4(0.f, 0.f, 0.f, 0.f);
    if ((unsigned)gy < HH) {
      if ((unsigned)gx0 <= (unsigned)(WW - 4)) {
        v = *reinterpret_cast<const float4*>(&ub[(size_t)gy * WW + gx0]);
      } else {
        if ((unsigned)gx0 < WW)       v.x = ub[(size_t)gy * WW + gx0];
        if ((unsigned)(gx0 + 1) < WW) v.y = ub[(size_t)gy * WW + gx0 + 1];
        if ((unsigned)(gx0 + 2) < WW) v.z = ub[(size_t)gy * WW + gx0 + 2];
        if ((unsigned)(gx0 + 3) < WW) v.w = ub[(size_t)gy * WW + gx0 + 3];
      }
    }
    unsigned p0 = (unsigned)f2bf(v.x) | ((unsigned)f2bf(v.y) << 16);
    unsigned p1 = (unsigned)f2bf(v.z) | ((unsigned)f2bf(v.w) << 16);
    *reinterpret_cast<uint2*>(&su2[r * 88 + g * 4]) = make_uint2(p0, p1);
  }
  // zero cols 80..87 (one uint4 per row, 16B-aligned: (r*88+80)*2 % 16 == 0)
  for (int idx = tid; idx < 58; idx += 512) {
    *reinterpret_cast<uint4*>(&su2[idx * 88 + 80]) = make_uint4(0u, 0u, 0u, 0u);
  }
  if (tid < 8) {  // finite-fill the +16 tail (read by row-57 over-reads)
    *reinterpret_cast<unsigned*>(&su2[58 * 88 + tid * 2]) = 0u;
  }
  // si: 36 rows x 35 float2-groups, window cols bx-2..bx+67 (8B-aligned)
  for (int idx = tid; idx < 36 * 35; idx += 512) {
    int i = idx / 35, g = idx % 35;
    int gy = by - 2 + i;
    int gx0 = bx - 2 + g * 2;
    float va = 0.f, vb = 0.f;
    if ((unsigned)gy < HH) {
      if ((unsigned)gx0 <= (unsigned)(WW - 2)) {
        float2 t = *reinterpret_cast<const float2*>(&ib[(size_t)gy * WW + gx0]);
        va = t.x; vb = t.y;
      } else {
        if ((unsigned)gx0 < WW)       va = ib[(size_t)gy * WW + gx0];
        if ((unsigned)(gx0 + 1) < WW) vb = ib[(size_t)gy * WW + gx0 + 1];
      }
    }
    si[i * 71 + g * 2]     = va;
    si[i * 71 + g * 2 + 1] = vb;
  }
  __syncthreads();

  // ---- phase 1a: edges on 34 rows x 66 cols (strips of 4), packed channels ----
  for (int idx = tid; idx < 34 * 17; idx += 512) {
    int i = idx % 34, j0 = (idx / 34) * 4;
    float2v acc2[4][4];
    #pragma unroll
    for (int c2 = 0; c2 < 4; ++c2)
      #pragma unroll
      for (int t = 0; t < 4; ++t) acc2[c2][t] = (float2v){0.f, 0.f};
    #pragma unroll
    for (int p = 0; p < 3; ++p) {
      float r[6];
      #pragma unroll
      for (int t = 0; t < 6; ++t) r[t] = si[(i + p) * 71 + j0 + t];
      #pragma unroll
      for (int qq = 0; qq < 3; ++qq) {
        const float* wb = &skf[(p * 3 + qq) * 8];
        float2v w0 = *reinterpret_cast<const float2v*>(wb + 0);
        float2v w1 = *reinterpret_cast<const float2v*>(wb + 2);
        float2v w2 = *reinterpret_cast<const float2v*>(wb + 4);
        float2v w3 = *reinterpret_cast<const float2v*>(wb + 6);
        #pragma unroll
        for (int t = 0; t < 4; ++t) {
          float2v v2 = {r[qq + t], r[qq + t]};
          acc2[0][t] = acc2[0][t] + v2 * w0;
          acc2[1][t] = acc2[1][t] + v2 * w1;
          acc2[2][t] = acc2[2][t] + v2 * w2;
          acc2[3][t] = acc2[3][t] + v2 * w3;
        }
      }
    }
    int gy = by - 1 + i;
    #pragma unroll
    for (int t = 0; t < 4; ++t) {
      int j = j0 + t;
      if (j < 66) {
        int gx = bx - 1 + j;
        float val = 0.f;
        if ((unsigned)gy < HH && (unsigned)gx < WW) {
          float2v e2 = pmax0(acc2[0][t]) + pmax0(acc2[1][t]) +
                       pmax0(acc2[2][t]) + pmax0(acc2[3][t]);
          float e = e2[0] + e2[1];
          val = e / (1.f + e);
        }
        sebf[i * 68 + j] = f2bf(val);
      }
    }
  }

  // ---- phase 1b: kappa via swapped-operand Toeplitz MFMA, 3x5=15 subtiles ----
  // (KT2 bank carries the k-n-1 shift for the bx-8 staging base.)
  {
    const unsigned short* KT = ((const unsigned short*)ws) + KT0 * 2;
    for (int s = wv; s < 15; s += 8) {
      int sty = s / 5, stx = s % 5;
      float4v acc = {0.f, 0.f, 0.f, 0.f};
      const unsigned short* arow = &su2[(sty * 16 + m) * 88 + stx * 16 + q * 8];
      #pragma unroll
      for (int a = 0; a < 11; ++a) {
        short8 bf = *reinterpret_cast<const short8*>(KT + (a * 64 + lane) * 8);
        short8 af = *reinterpret_cast<const short8*>(arow + a * 88);
        acc = __builtin_amdgcn_mfma_f32_16x16x32_bf16(af, bf, acc, 0, 0, 0);
      }
      #pragma unroll
      for (int i = 0; i < 4; ++i) {
        int rl = sty * 16 + q * 4 + i, cl = stx * 16 + m;
        if (rl < 36 && cl < 68) {
          int yy = by - 2 + rl, xx = bx - 2 + cl;
          float v = 0.f;
          if ((unsigned)yy < HH && (unsigned)xx < WW)
            v = acc[i] * kk[(size_t)yy * WW + xx];
          skp[rl * 69 + cl] = v;
        }
      }
    }
  }
  __syncthreads();

  // ---- phase 2: grads via 32x32x16 MFMA + split combine ----
  // Wave wv owns pixel rows wv*4 .. wv*4+3.
  {
    const unsigned short* F = ((const unsigned short*)ws) + F0 * 2;
    short8 afx = *reinterpret_cast<const short8*>(F + lane * 8);
    short8 afy = *reinterpret_cast<const short8*>(F + (64 + lane) * 8);

    const int c    = lane & 31;
    const int half = lane >> 5;
    const int R0   = wv * 4;              // wave's base pixel row

    #pragma unroll
    for (int h = 0; h < 2; ++h) {
      const int cl = h * 32 + c;            // pixel col (tile-local, 0..63)
      unsigned short W[9];
      #pragma unroll
      for (int d = 0; d < 3; ++d) {
        const unsigned short* rp = &sebf[(R0 + d) * 68 + cl];
        W[3 * d + 0] = rp[0]; W[3 * d + 1] = rp[1]; W[3 * d + 2] = rp[2];
      }

      float rxv[4], ryv[4];
      #pragma unroll
      for (int r = 0; r < 4; ++r) {
        short8 bv = (short8)0;
        if (half == 0) {
          #pragma unroll
          for (int j = 0; j < 8; ++j) bv[j] = (short)W[j];
        } else {
          bv[0] = (short)W[8];
        }

        // sequence through ONE accumulator: cx retires before cy allocates
        float16v cacc = {0.f, 0.f, 0.f, 0.f, 0.f, 0.f, 0.f, 0.f,
                         0.f, 0.f, 0.f, 0.f, 0.f, 0.f, 0.f, 0.f};
        cacc = __builtin_amdgcn_mfma_f32_32x32x16_bf16(afx, bv, cacc, 0, 0, 0);
        float rx = rsum16(cacc);
        cacc = (float16v){0.f, 0.f, 0.f, 0.f, 0.f, 0.f, 0.f, 0.f,
                          0.f, 0.f, 0.f, 0.f, 0.f, 0.f, 0.f, 0.f};
        cacc = __builtin_amdgcn_mfma_f32_32x32x16_bf16(afy, bv, cacc, 0, 0, 0);
        float ry = rsum16(cacc);

        rx += __shfl_xor(rx, 32);
        ry += __shfl_xor(ry, 32);
        rxv[r] = rx; ryv[r] = ry;

        if (r < 3) {
          #pragma unroll
          for (int t = 0; t < 6; ++t) W[t] = W[t + 3];
          const unsigned short* rp = &sebf[(R0 + r + 3) * 68 + cl];
          W[6] = rp[0]; W[7] = rp[1]; W[8] = rp[2];
        }
      }

      // combine: lane half -> rows B..B+1, B = R0 + 2*half, col cl
      {
        const int B = R0 + 2 * half;
        const int gx = bx + cl;

        float kap[2] = {0.f, 0.f};
        #pragma unroll
        for (int ii = 0; ii < 6; ++ii) {
          float rowv[5];
          #pragma unroll
          for (int n = 0; n < 5; ++n) rowv[n] = skp[(B + ii) * 69 + cl + n];
          #pragma unroll
          for (int rr = 0; rr < 2; ++rr) {
            const int m5 = ii - rr;
            if (m5 >= 0 && m5 < 5) {
              #pragma unroll
              for (int n = 0; n < 5; ++n)
                kap[rr] = fmaf(rowv[n], sm[m5 * 5 + n], kap[rr]);
            }
          }
        }

        float ucv[3];
        #pragma unroll
        for (int t = 0; t < 3; ++t) {
          int gy = by + B + t;
          ucv[t] = (gy < HH) ? ub[(size_t)gy * WW + gx] : 0.f;
        }

        #pragma unroll
        for (int rr = 0; rr < 2; ++rr) {
          const int oy = B + rr;
          const int gy = by + oy;
          float uc = ucv[rr];
          float ul = gx > 0 ? ub[(size_t)gy * WW + gx - 1] : 0.f;
          float ud = ucv[rr + 1];          // 0 at gy==HH-1 via guard above
          float ec = bf2f(sebf[(oy + 1) * 68 + cl + 1]);
          float xp = uc - ul;
          float yp = uc - ud;
          out[((size_t)b * HH + gy) * WW + gx] =
              uc + rxv[2 * half + rr] * xp + ryv[2 * half + rr] * yp + ec + kap[rr];
        }
      }
    }
  }
}

// ---------------- Fallback: R3 monolith (used if ws too small) --------------
__global__ __launch_bounds__(256) void forcing_main(
    const float* __restrict__ u, const float* __restrict__ img,
    const float* __restrict__ kx, const float* __restrict__ ky,
    const float* __restrict__ sm, const float* __restrict__ kk,
    const float* __restrict__ ws, float* __restrict__ out) {
  __shared__ float su[46][48];
  __shared__ float si[36][37];
  __shared__ float se[34][35];
  __shared__ float sk[36][37];
  __shared__ float w_edge[72];
  __shared__ float w_kx[288];
  __shared__ float w_ky[288];
  __shared__ float w_k11[124];
  __shared__ float w_sm[28];

  const int bx = blockIdx.x * 32;
  const int by = blockIdx.y * 32;
  const int b  = blockIdx.z;
  const int tid = threadIdx.x;
  const float* ub = u   + (size_t)b * HH * WW;
  const float* ib = img + (size_t)b * HH * WW;

  for (int i = tid; i < 72; i += 256)  w_edge[i] = ws[i];
  for (int i = tid; i < 121; i += 256) w_k11[i]  = ws[72 + i];
  for (int i = tid; i < 288; i += 256) { w_kx[i] = kx[i]; w_ky[i] = ky[i]; }
  if (tid < 25) w_sm[tid] = sm[tid];

  for (int idx = tid; idx < 46 * 46; idx += 256) {
    int i = idx / 46, j = idx % 46;
    int gy = by - 7 + i, gx = bx - 7 + j;
    float v = 0.f;
    if ((unsigned)gy < HH && (unsigned)gx < WW) v = ub[gy * WW + gx];
    su[i][j] = v;
  }
  for (int idx = tid; idx < 36 * 36; idx += 256) {
    int i = idx / 36, j = idx % 36;
    int gy = by - 2 + i, gx = bx - 2 + j;
    float v = 0.f;
    if ((unsigned)gy < HH && (unsigned)gx < WW) v = ib[gy * WW + gx];
    si[i][j] = v;
  }
  __syncthreads();

  for (int idx = tid; idx < 34 * 9; idx += 256) {
    int i = idx / 9, j0 = (idx % 9) * 4;
    float acc[8][4];
    #pragma unroll
    for (int c = 0; c < 8; ++c)
      #pragma unroll
      for (int t = 0; t < 4; ++t) acc[c][t] = 0.f;
    #pragma unroll
    for (int p = 0; p < 3; ++p) {
      float r[6];
      #pragma unroll
      for (int t = 0; t < 6; ++t) r[t] = si[i + p][j0 + t];
      #pragma unroll
      for (int q = 0; q < 3; ++q) {
        const float4 w0 = *reinterpret_cast<const float4*>(&w_edge[(p * 3 + q) * 8]);
        const float4 w1 = *reinterpret_cast<const float4*>(&w_edge[(p * 3 + q) * 8 + 4]);
        #pragma unroll
        for (int t = 0; t < 4; ++t) {
          float v = r[q + t];
          acc[0][t] = fmaf(v, w0.x, acc[0][t]);
          acc[1][t] = fmaf(v, w0.y, acc[1][t]);
          acc[2][t] = fmaf(v, w0.z, acc[2][t]);
          acc[3][t] = fmaf(v, w0.w, acc[3][t]);
          acc[4][t] = fmaf(v, w1.x, acc[4][t]);
          acc[5][t] = fmaf(v, w1.y, acc[5][t]);
          acc[6][t] = fmaf(v, w1.z, acc[6][t]);
          acc[7][t] = fmaf(v, w1.w, acc[7][t]);
        }
      }
    }
    int gy = by - 1 + i;
    #pragma unroll
    for (int t = 0; t < 4; ++t) {
      int j = j0 + t;
      if (j < 34) {
        int gx = bx - 1 + j;
        float val = 0.f;
        if ((unsigned)gy < HH && (unsigned)gx < WW) {
          float e = 0.f;
          #pragma unroll
          for (int c = 0; c < 8; ++c) e += fmaxf(acc[c][t], 0.f);
          val = e / (1.f + e);
        }
        se[i][j] = val;
      }
    }
  }

  for (int idx = tid; idx < 36 * 9; idx += 256) {
    int i = idx / 9, js = (idx % 9) * 4;
    float o0 = 0.f, o1 = 0.f, o2 = 0.f, o3 = 0.f;
    #pragma unroll
    for (int A = 0; A < 11; ++A) {
      const float* row = &su[i + A][js];
      float4 v0 = *reinterpret_cast<const float4*>(row);
      float4 v1 = *reinterpret_cast<const float4*>(row + 4);
      float4 v2 = *reinterpret_cast<const float4*>(row + 8);
      float r[14] = {v0.x, v0.y, v0.z, v0.w, v1.x, v1.y, v1.z, v1.w,
                     v2.x, v2.y, v2.z, v2.w, row[12], row[13]};
      #pragma unroll
      for (int B2 = 0; B2 < 11; ++B2) {
        float w = w_k11[A * 11 + B2];
        o0 = fmaf(r[B2],     w, o0);
        o1 = fmaf(r[B2 + 1], w, o1);
        o2 = fmaf(r[B2 + 2], w, o2);
        o3 = fmaf(r[B2 + 3], w, o3);
      }
    }
    int gy = by - 2 + i;
    float o[4] = {o0, o1, o2, o3};
    #pragma unroll
    for (int t = 0; t < 4; ++t) {
      int gx = bx - 2 + js + t;
      float val = 0.f;
      if ((unsigned)gy < HH && (unsigned)gx < WW) val = o[t] * kk[gy * WW + gx];
      sk[i][js + t] = val;
    }
  }
  __syncthreads();

  {
    const int oy = tid >> 3;
    const int ox = (tid & 7) * 4;
    const int gy = by + oy;
    const int gx = bx + ox;

    float e[3][6];
    #pragma unroll
    for (int p = 0; p < 3; ++p)
      #pragma unroll
      for (int t = 0; t < 6; ++t) e[p][t] = se[oy + p][ox + t];

    const float4* wx4 = reinterpret_cast<const float4*>(w_kx);
    const float4* wy4 = reinterpret_cast<const float4*>(w_ky);

    float gxa[4] = {0.f, 0.f, 0.f, 0.f};
    float gya[4] = {0.f, 0.f, 0.f, 0.f};
    #pragma unroll
    for (int cq = 0; cq < 8; ++cq) {
      float sx[4][4], sy[4][4];
      #pragma unroll
      for (int cc = 0; cc < 4; ++cc)
        #pragma unroll
        for (int t = 0; t < 4; ++t) { sx[cc][t] = 0.f; sy[cc][t] = 0.f; }
      #pragma unroll
      for (int p = 0; p < 3; ++p)
        #pragma unroll
        for (int q = 0; q < 3; ++q) {
          float4 wx = wx4[(p * 3 + q) * 8 + cq];
          float4 wy = wy4[(p * 3 + q) * 8 + cq];
          #pragma unroll
          for (int t = 0; t < 4; ++t) {
            float evv = e[p][q + t];
            sx[0][t] = fmaf(evv, wx.x, sx[0][t]);
            sx[1][t] = fmaf(evv, wx.y, sx[1][t]);
            sx[2][t] = fmaf(evv, wx.z, sx[2][t]);
            sx[3][t] = fmaf(evv, wx.w, sx[3][t]);
            sy[0][t] = fmaf(evv, wy.x, sy[0][t]);
            sy[1][t] = fmaf(evv, wy.y, sy[1][t]);
            sy[2][t] = fmaf(evv, wy.z, sy[2][t]);
            sy[3][t] = fmaf(evv, wy.w, sy[3][t]);
          }
        }
      #pragma unroll
      for (int cc = 0; cc < 4; ++cc)
        #pragma unroll
        for (int t = 0; t < 4; ++t) {
          gxa[t] += fmaxf(sx[cc][t], 0.f);
          gya[t] += fmaxf(sy[cc][t], 0.f);
        }
    }

    float res[4];
    #pragma unroll
    for (int t = 0; t < 4; ++t) {
      float kap = 0.f;
      #pragma unroll
      for (int m = 0; m < 5; ++m)
        #pragma unroll
        for (int n = 0; n < 5; ++n)
          kap = fmaf(sk[oy + m][ox + t + n], w_sm[m * 5 + n], kap);

      float uc = su[oy + 7][ox + 7 + t];
      float xp = uc - su[oy + 7][ox + 6 + t];
      float yp = uc - su[oy + 8][ox + 7 + t];
      float ec = se[oy + 1][ox + 1 + t];
      res[t] = uc + gxa[t] * xp + gya[t] * yp + ec + kap;
    }

    float4 r4 = make_float4(res[0], res[1], res[2], res[3]);
    *reinterpret_cast<float4*>(&out[((size_t)b * HH + gy) * WW + gx]) = r4;
  }
}

extern "C" void kernel_launch(void* const* d_in, const int* in_sizes, int n_in,
                              void* d_out, int out_size, void* d_ws, size_t ws_size,
                              hipStream_t stream) {
  const float* u   = (const float*)d_in[0];
  const float* img = (const float*)d_in[1];
  const float* kx  = (const float*)d_in[2];
  const float* ky  = (const float*)d_in[3];
  const float* kd  = (const float*)d_in[4];
  const float* kp  = (const float*)d_in[5];
  const float* k0  = (const float*)d_in[6];
  const float* k1  = (const float*)d_in[7];
  const float* k2  = (const float*)d_in[8];
  const float* sm  = (const float*)d_in[9];
  const float* kk  = (const float*)d_in[10];
  float* out = (float*)d_out;
  float* ws  = (float*)d_ws;

  precompute_kernels<<<1, 1024, 0, stream>>>(kd, kp, k0, k1, k2, kx, ky, ws);
  if (ws != nullptr && ws_size >= WS_NEEDED_BYTES) {
    dim3 grid(WW / TX, HH / TY, BB);
    fused<<<grid, 512, 0, stream>>>(u, img, kk, sm, ws, out);
  } else {
    dim3 grid(WW / 32, HH / 32, BB);
    forcing_main<<<grid, 256, 0, stream>>>(u, img, kx, ky, sm, kk, ws, out);
  }
}